// Round 10
// baseline (42285.498 us; speedup 1.0000x reference)
//
#include <hip/hip_runtime.h>
#include <math.h>

#define TT 2048
#define DIN 64
#define HH 256

typedef __attribute__((ext_vector_type(8))) short bf16x8;
typedef __attribute__((ext_vector_type(4))) float f32x4;
typedef __attribute__((ext_vector_type(4))) unsigned u32x4;
typedef unsigned short u16;
typedef unsigned u32t;

// ---- LDS layout (shorts region, then floats region) ----
// W-lo fragments lane-linear: [kt][tile][lane][8] -> contiguous 1KB/wave reads.
// h/x staged in r4-proven padded row layout (2-way banks, free).
#define OFF_W0LO 0                    // 10kt*4t*64*8 = 20480 shorts
#define OFF_W1LO 20480                // 16kt*4t*64*8 = 32768
#define OFF_H    53248                // 4 planes * 16 rows * 264 = 16896
#define OFF_X    70144                // 2 par * (hi 1152 + lo 1152) = 4608
#define SH_SHORTS 74752
#define SH_BYTES (SH_SHORTS*2)        // 149504 B
#define GB_STR 68                     // gate buffer row stride (64 + 4 pad)
#define LDS_BYTES (SH_BYTES + 2304*4) // + gb0,gb1,biases = 158720 B

#define HS_STR 264
#define XS_STR 72

__device__ __forceinline__ u16 f2bf(float f){
    u32t u = __builtin_bit_cast(u32t, f);
    u += 0x7fffu + ((u >> 16) & 1u);   // RNE
    return (u16)(u >> 16);
}
__device__ __forceinline__ float bf2f(u16 h){
    u32t u = ((u32t)h) << 16;
    return __builtin_bit_cast(float, u);
}
__device__ __forceinline__ float sigf(float v){ return 1.0f/(1.0f+__expf(-v)); }
__device__ __forceinline__ float tanh_fast(float v){
    float x = fminf(fmaxf(v, -20.f), 20.f);
    float t = __expf(2.f*x);
    return (t - 1.f) / (t + 1.f);
}
__device__ __forceinline__ void split8(float4 a, float4 b, bf16x8& hi, bf16x8& lo){
    float v[8] = {a.x,a.y,a.z,a.w,b.x,b.y,b.z,b.w};
    #pragma unroll
    for (int j=0;j<8;++j){
        u16 h = f2bf(v[j]);
        hi[j] = (short)h;
        lo[j] = (short)f2bf(v[j] - bf2f(h));
    }
}

// Barrier: release store to own slot (r7-proven); 16-lane RELAXED polls
// (no per-poll invalidate); single acquire fence after success.
__device__ __forceinline__ void group_barrier(u32t* flg, int wgin, unsigned epoch){
    __syncthreads();   // each wave drains vmcnt(0) before s_barrier -> publishes acked
    if (threadIdx.x == 0)
        __hip_atomic_store(flg + wgin*16, epoch, __ATOMIC_RELEASE, __HIP_MEMORY_SCOPE_AGENT);
    if (threadIdx.x < 16){
        while (__hip_atomic_load(flg + threadIdx.x*16, __ATOMIC_RELAXED, __HIP_MEMORY_SCOPE_AGENT) < epoch)
            __builtin_amdgcn_s_sleep(1);
    }
    __builtin_amdgcn_fence(__ATOMIC_ACQUIRE, "agent");
    __syncthreads();
}

#define MFMA16(a,b,c_) __builtin_amdgcn_mfma_f32_16x16x32_bf16(a,b,c_,0,0,0)

__global__ __launch_bounds__(512, 1)
void lstm_v10(const float* __restrict__ x,
              const float* __restrict__ Wih0, const float* __restrict__ Whh0,
              const float* __restrict__ bih0, const float* __restrict__ bhh0,
              const float* __restrict__ Wih1, const float* __restrict__ Whh1,
              const float* __restrict__ bih1, const float* __restrict__ bhh1,
              const float* __restrict__ Wd,   const float* __restrict__ bd,
              float* __restrict__ out, u16* __restrict__ hb,
              u32t* __restrict__ flags)
{
    extern __shared__ char smem[];
    short* sh = (short*)smem;
    float* sf = (float*)(smem + SH_BYTES);
    float* gb0 = sf;              // [16][68]
    float* gb1 = sf + 1088;       // [16][68]
    float* bs  = sf + 2176;       // [2][64]

    const int tid = threadIdx.x;
    const int w   = blockIdx.x;
    const int grp  = w & 15;      // row-group: rows 16*grp .. +15 (one XCD under %8 rr)
    const int wgin = w >> 4;      // 0..15 -> units 16*wgin .. +15
    const int grpbase = grp * 16;
    const int ubase   = wgin * 16;

    u32t* flg = flags + grp * 256;   // 16 slots x 64B

    // h planes (u16): h0hi(0) h0lo(131072) h1hi(262144) h1lo(393216), +parity*65536

    const int l   = tid & 63;
    const int wid = tid >> 6;       // 8 waves
    const int lay = wid >> 2;       // 0: layer0 tile, 1: layer1 tile
    const int nt  = wid & 3;        // tile (4 units x 4 gates = 16 cols)
    const int c   = l & 15, ks = l >> 4;
    const int b   = c & 3;                    // gate
    const int un  = ubase + nt*4 + (c >> 2);  // hidden unit
    const int G   = b*HH + un;                // weight row

    // ---- stationary HI weight fragments in registers ----
    bf16x8 wh[16];
    if (lay == 0){
        #pragma unroll
        for (int kt = 0; kt < 10; ++kt){
            int k = kt*32 + ks*8;
            const float* p = (k < 64) ? (Wih0 + (size_t)G*DIN + k)
                                      : (Whh0 + (size_t)G*HH + (k - 64));
            bf16x8 hi_, lo_; split8(*(const float4*)p, *(const float4*)(p+4), hi_, lo_);
            wh[kt] = hi_;
        }
    } else {
        #pragma unroll
        for (int kt = 0; kt < 16; ++kt){
            int k = kt*32 + ks*8;
            const float* p = (k < 256) ? (Wih1 + (size_t)G*HH + k)
                                       : (Whh1 + (size_t)G*HH + (k - 256));
            bf16x8 hi_, lo_; split8(*(const float4*)p, *(const float4*)(p+4), hi_, lo_);
            wh[kt] = hi_;
        }
    }

    // ---- LO weight fragments -> LDS [kt][nt][lane][8] ----
    for (int f = tid; f < 2560; f += 512){
        int l2 = f & 63, nt2 = (f>>6)&3, kt2 = f>>8;
        int c2 = l2 & 15, ks2 = l2 >> 4;
        int G2 = (c2&3)*HH + ubase + nt2*4 + (c2>>2);
        int k  = kt2*32 + ks2*8;
        const float* p = (k < 64) ? (Wih0 + (size_t)G2*DIN + k)
                                  : (Whh0 + (size_t)G2*HH + (k - 64));
        bf16x8 hi_, lo_; split8(*(const float4*)p, *(const float4*)(p+4), hi_, lo_);
        *(bf16x8*)(sh + OFF_W0LO + f*8) = lo_;
    }
    for (int f = tid; f < 4096; f += 512){
        int l2 = f & 63, nt2 = (f>>6)&3, kt2 = f>>8;
        int c2 = l2 & 15, ks2 = l2 >> 4;
        int G2 = (c2&3)*HH + ubase + nt2*4 + (c2>>2);
        int k  = kt2*32 + ks2*8;
        const float* p = (k < 256) ? (Wih1 + (size_t)G2*HH + k)
                                   : (Whh1 + (size_t)G2*HH + (k - 256));
        bf16x8 hi_, lo_; split8(*(const float4*)p, *(const float4*)(p+4), hi_, lo_);
        *(bf16x8*)(sh + OFF_W1LO + f*8) = lo_;
    }

    // ---- biases [layer][u*4+g] ----
    if (tid < 128){
        int layb = tid >> 6, col = tid & 63;
        int Gb = (col&3)*HH + ubase + (col>>2);
        bs[layb*64 + col] = layb ? (bih1[Gb] + bhh1[Gb]) : (bih0[Gb] + bhh0[Gb]);
    }
    // ---- zero my WG's h slots, all planes/parities (ws poisoned) ----
    #pragma unroll
    for (int j = 0; j < 4; ++j){
        int idx = j*512 + tid;                // 0..2047
        int s = idx >> 8;                      // plane*2+parity
        int cell = idx & 255;
        int row = cell >> 4, uq = cell & 15;
        *(volatile u16*)(hb + (size_t)(s>>1)*131072 + (s&1)*65536
                         + (size_t)(grpbase+row)*HH + ubase + uq) = 0;
    }
    // ---- stage x(0) into parity 0 ----
    if (tid < 128){
        int r = tid >> 3, k8 = tid & 7;
        const float* xp = x + (size_t)(grpbase + r)*(TT*DIN) + k8*8;
        bf16x8 xh, xl; split8(*(const float4*)xp, *(const float4*)(xp+4), xh, xl);
        *(bf16x8*)(sh + OFF_X + r*XS_STR + k8*8)        = xh;
        *(bf16x8*)(sh + OFF_X + 1152 + r*XS_STR + k8*8) = xl;
    }
    group_barrier(flg, wgin, 1u);

    // A-frag / B-lo lane pointers
    const short* hA   = sh + OFF_H + c*HS_STR + ks*8;       // + plane*4224 + kt*32
    const short* w0lo = sh + OFF_W0LO + (nt*64 + l)*8;      // + kt*2048
    const short* w1lo = sh + OFF_W1LO + (nt*64 + l)*8;
    float* gwp = (lay ? gb1 : gb0) + (ks*4)*GB_STR + nt*16 + c;

    // update mapping: 1 cell/thread
    const int ulay = tid >> 8;                 // 0: layer0, 1: layer1
    const int cell = tid & 255;
    const int urow = cell >> 4, uun = cell & 15;
    const size_t poff = (size_t)(grpbase + urow)*HH + ubase + uun;
    const float* gbu = (ulay ? gb1 : gb0) + urow*GB_STR + uun*4;
    const float4 bb = *(const float4*)(bs + ulay*64 + uun*4);
    float cs = 0.f;

    for (int k = 0; k <= TT; ++k){
        // ---- stage h0(k-1), h1(k-2): 4 volatile uint4 loads/thread (32KB) ----
        {
            const unsigned rdo = ((k + 1) & 1) * 65536u;
            int row = tid >> 5, sl = tid & 31;
            size_t goff = (size_t)(grpbase + row)*HH + sl*8;
            int loff = row*HS_STR + sl*8;
            u32x4 v0 = *(const volatile u32x4*)(hb + rdo + goff);
            u32x4 v1 = *(const volatile u32x4*)(hb + 131072 + rdo + goff);
            u32x4 v2 = *(const volatile u32x4*)(hb + 262144 + rdo + goff);
            u32x4 v3 = *(const volatile u32x4*)(hb + 393216 + rdo + goff);
            *(u32x4*)(sh + OFF_H + loff)          = v0;
            *(u32x4*)(sh + OFF_H + 4224 + loff)   = v1;
            *(u32x4*)(sh + OFF_H + 8448 + loff)   = v2;
            *(u32x4*)(sh + OFF_H + 12672 + loff)  = v3;
        }
        __syncthreads();

        // ---- compute: one 16x16 tile-job per wave ----
        if (lay == 0){
            if (k < TT){
                f32x4 ac[4] = {};
                const short* xb = sh + OFF_X + (k&1)*2304 + c*XS_STR + ks*8;
                #pragma unroll
                for (int kt = 0; kt < 10; ++kt){
                    bf16x8 ah, al;
                    if (kt < 2){
                        ah = *(const bf16x8*)(xb + kt*32);
                        al = *(const bf16x8*)(xb + 1152 + kt*32);
                    } else {
                        ah = *(const bf16x8*)(hA + (kt-2)*32);
                        al = *(const bf16x8*)(hA + 4224 + (kt-2)*32);
                    }
                    bf16x8 wl = *(const bf16x8*)(w0lo + kt*2048);
                    const int q = kt & 3;
                    ac[q] = MFMA16(ah, wh[kt], ac[q]);
                    ac[q] = MFMA16(al, wh[kt], ac[q]);
                    ac[q] = MFMA16(ah, wl,     ac[q]);
                }
                f32x4 aa = (ac[0] + ac[1]) + (ac[2] + ac[3]);
                gwp[0]        = aa[0];
                gwp[GB_STR]   = aa[1];
                gwp[2*GB_STR] = aa[2];
                gwp[3*GB_STR] = aa[3];
            }
        } else {
            if (k >= 1){
                f32x4 ac[4] = {};
                #pragma unroll
                for (int kt = 0; kt < 16; ++kt){
                    bf16x8 ah, al;
                    if (kt < 8){
                        ah = *(const bf16x8*)(hA + kt*32);
                        al = *(const bf16x8*)(hA + 4224 + kt*32);
                    } else {
                        ah = *(const bf16x8*)(hA + 8448 + (kt-8)*32);
                        al = *(const bf16x8*)(hA + 12672 + (kt-8)*32);
                    }
                    bf16x8 wl = *(const bf16x8*)(w1lo + kt*2048);
                    const int q = kt & 3;
                    ac[q] = MFMA16(ah, wh[kt], ac[q]);
                    ac[q] = MFMA16(al, wh[kt], ac[q]);
                    ac[q] = MFMA16(ah, wl,     ac[q]);
                }
                f32x4 aa = (ac[0] + ac[1]) + (ac[2] + ac[3]);
                gwp[0]        = aa[0];
                gwp[GB_STR]   = aa[1];
                gwp[2*GB_STR] = aa[2];
                gwp[3*GB_STR] = aa[3];
            }
        }
        __syncthreads();

        // ---- cell update: 1 cell/thread, float4 gates + float4 bias ----
        const unsigned wro = (k & 1) * 65536u;
        const bool uact = ulay ? (k >= 1) : (k < TT);
        if (uact){
            float4 g4 = *(const float4*)gbu;
            float gi = g4.x + bb.x, gf = g4.y + bb.y;
            float gg = g4.z + bb.z, go = g4.w + bb.w;
            cs = sigf(gf)*cs + sigf(gi)*tanh_fast(gg);
            float hn = sigf(go)*tanh_fast(cs);
            u16 hh_ = f2bf(hn);
            u16 hl_ = f2bf(hn - bf2f(hh_));
            const unsigned pb = ulay ? 262144u : 0u;
            *(volatile u16*)(hb + pb + wro + poff)           = hh_;
            *(volatile u16*)(hb + pb + 131072 + wro + poff)  = hl_;
        }
        // ---- prefetch-stage x(k+1) ----
        if (k + 1 < TT && tid < 128){
            int r = tid >> 3, k8 = tid & 7;
            const float* xp = x + (size_t)(grpbase + r)*(TT*DIN) + (size_t)(k+1)*DIN + k8*8;
            bf16x8 xh, xl; split8(*(const float4*)xp, *(const float4*)(xp+4), xh, xl);
            int pbx = ((k+1)&1)*2304;
            *(bf16x8*)(sh + OFF_X + pbx + r*XS_STR + k8*8)        = xh;
            *(bf16x8*)(sh + OFF_X + pbx + 1152 + r*XS_STR + k8*8) = xl;
        }
        group_barrier(flg, wgin, (unsigned)(k + 2));
    }

    // ---- dense head: out = h1(TT-1) @ Wd^T + bd ; parity 0 planes ----
    if (wgin == 0 && tid < 32){
        int r = tid >> 1, j = tid & 1;
        const u16* hhp = hb + 262144 + (size_t)(grpbase + r)*HH;
        const u16* hlp = hb + 393216 + (size_t)(grpbase + r)*HH;
        const float* wdp = Wd + j*HH;
        float a = bd[j];
        #pragma unroll 4
        for (int q = 0; q < HH; ++q)
            a += (bf2f(*(const volatile u16*)(hhp + q)) +
                  bf2f(*(const volatile u16*)(hlp + q))) * wdp[q];
        out[(grpbase + r)*2 + j] = a;
    }
}

extern "C" void kernel_launch(void* const* d_in, const int* in_sizes, int n_in,
                              void* d_out, int out_size, void* d_ws, size_t ws_size,
                              hipStream_t stream) {
    const float* x    = (const float*)d_in[0];
    const float* Wih0 = (const float*)d_in[1];
    const float* Whh0 = (const float*)d_in[2];
    const float* bih0 = (const float*)d_in[3];
    const float* bhh0 = (const float*)d_in[4];
    const float* Wih1 = (const float*)d_in[5];
    const float* Whh1 = (const float*)d_in[6];
    const float* bih1 = (const float*)d_in[7];
    const float* bhh1 = (const float*)d_in[8];
    const float* Wd   = (const float*)d_in[9];
    const float* bd   = (const float*)d_in[10];
    float* out = (float*)d_out;

    u32t* flags = (u32t*)d_ws;                     // 16 groups x 16 slots x 64B
    u16* hb = (u16*)((char*)d_ws + 32768);         // 1 MB h hi/lo planes

    hipMemsetAsync(d_ws, 0, 32768, stream);

    hipFuncSetAttribute((const void*)lstm_v10,
                        hipFuncAttributeMaxDynamicSharedMemorySize, LDS_BYTES);

    lstm_v10<<<dim3(256), dim3(512), LDS_BYTES, stream>>>(
        x, Wih0, Whh0, bih0, bhh0, Wih1, Whh1, bih1, bhh1,
        Wd, bd, out, hb, flags);
}

// Round 11
// 21370.901 us; speedup vs baseline: 1.9786x; 1.9786x over previous
//
#include <hip/hip_runtime.h>
#include <math.h>

#define TT 2048
#define DIN 64
#define HH 256

typedef __attribute__((ext_vector_type(8))) short bf16x8;
typedef __attribute__((ext_vector_type(4))) float f32x4;
typedef __attribute__((ext_vector_type(4))) unsigned u32x4;
typedef unsigned short u16;
typedef unsigned u32t;

// ---- LDS layout (shorts region, then floats) ----
// h staged in FRAGMENT order: region + kt*1024 + mt*512 + l*8 is lane-linear.
#define LH0HI 0
#define LH0LO 8192
#define LH1HI 16384
#define LH1LO 24576
#define LX    32768              // + par*4096 ; hi +0, lo +2048 (ks^(c&3) swizzle)
#define LW0LO 40960              // [kt10][nt2*64+ks*16+c][8] = 10240 shorts
#define SH_SHORTS 51200
#define SH_BYTES (SH_SHORTS*2)   // 102400 B
// floats: gbT0 [32col][33] = 1056, gbT1 = 1056, b0s 32, b1s 32
#define LDS_BYTES (SH_BYTES + 2176*4)   // 111104 B

__device__ __forceinline__ u16 f2bf(float f){
    u32t u = __builtin_bit_cast(u32t, f);
    u += 0x7fffu + ((u >> 16) & 1u);   // RNE
    return (u16)(u >> 16);
}
__device__ __forceinline__ float bf2f(u16 h){
    u32t u = ((u32t)h) << 16;
    return __builtin_bit_cast(float, u);
}
__device__ __forceinline__ float sigf(float v){ return 1.0f/(1.0f+__expf(-v)); }
__device__ __forceinline__ float tanh_fast(float v){
    float x = fminf(fmaxf(v, -20.f), 20.f);
    float t = __expf(2.f*x);
    return (t - 1.f) / (t + 1.f);
}
__device__ __forceinline__ void split8(float4 a, float4 b, bf16x8& hi, bf16x8& lo){
    float v[8] = {a.x,a.y,a.z,a.w,b.x,b.y,b.z,b.w};
    #pragma unroll
    for (int j=0;j<8;++j){
        u16 h = f2bf(v[j]);
        hi[j] = (short)h;
        lo[j] = (short)f2bf(v[j] - bf2f(h));
    }
}

// v9-proven: release store to own 64B slot + 32-lane acquire poll.
__device__ __forceinline__ void group_barrier(u32t* flg, int ug, unsigned epoch){
    __syncthreads();
    if (threadIdx.x == 0)
        __hip_atomic_store(flg + ug*16, epoch, __ATOMIC_RELEASE, __HIP_MEMORY_SCOPE_AGENT);
    if (threadIdx.x < 32){
        while (__hip_atomic_load(flg + threadIdx.x*16, __ATOMIC_ACQUIRE, __HIP_MEMORY_SCOPE_AGENT) < epoch)
            __builtin_amdgcn_s_sleep(1);
    }
    __syncthreads();
}

#define MFMA16(a,b,c_) __builtin_amdgcn_mfma_f32_16x16x32_bf16(a,b,c_,0,0,0)

__global__ __launch_bounds__(256, 1)
void lstm_v11(const float* __restrict__ x,
              const float* __restrict__ Wih0, const float* __restrict__ Whh0,
              const float* __restrict__ bih0, const float* __restrict__ bhh0,
              const float* __restrict__ Wih1, const float* __restrict__ Whh1,
              const float* __restrict__ bih1, const float* __restrict__ bhh1,
              const float* __restrict__ Wd,   const float* __restrict__ bd,
              float* __restrict__ out, u16* __restrict__ hb,
              u32t* __restrict__ flags)
{
    extern __shared__ char smem[];
    short* sh  = (short*)smem;
    float* sf  = (float*)(smem + SH_BYTES);
    float* gbT0 = sf;             // [32 col][33]
    float* gbT1 = sf + 1056;      // [32 col][33]
    float* b0s  = sf + 2112;      // [32]
    float* b1s  = sf + 2144;      // [32]

    const int tid = threadIdx.x;
    const int w   = blockIdx.x;
    const int rb  = w & 7;      // row-group (same XCD under %8 round-robin)
    const int ug  = w >> 3;     // unit-group 0..31
    const int rbase = rb * 32;
    const int u0  = ug * 8;

    u32t* flg = flags + rb * 512;

    // Global h: per-group fragment-order slices, 8192 shorts each.
    // base = rb*65536 + s*8192 ; s: h0hi=0+p, h0lo=2+p, h1hi=4+p, h1lo=6+p
    u16* gbase = hb + (size_t)rb * 65536;

    const int l  = tid & 63;
    const int wv = tid >> 6;
    const int mt = wv >> 1, nt = wv & 1;
    const int c  = l & 15, ks = l >> 4;
    const int gbx = nt*2 + (c >> 3);
    const int g   = gbx*HH + u0 + (c & 7);

    // ---- stationary weight fragments: hi all in regs; lo: W1 in regs, W0 in LDS ----
    bf16x8 w0h[10];
    #pragma unroll
    for (int kt = 0; kt < 10; ++kt){
        int k = kt*32 + ks*8;
        const float* p = (k < 64) ? (Wih0 + (size_t)g*DIN + k)
                                  : (Whh0 + (size_t)g*HH + (k - 64));
        bf16x8 hi_, lo_; split8(*(const float4*)p, *(const float4*)(p+4), hi_, lo_);
        w0h[kt] = hi_;
    }
    bf16x8 w1h[16], w1l[16];
    #pragma unroll
    for (int kt = 0; kt < 16; ++kt){
        int k = kt*32 + ks*8;
        const float* p = (k < 256) ? (Wih1 + (size_t)g*HH + k)
                                   : (Whh1 + (size_t)g*HH + (k - 256));
        bf16x8 hi_, lo_; split8(*(const float4*)p, *(const float4*)(p+4), hi_, lo_);
        w1h[kt] = hi_; w1l[kt] = lo_;
    }
    // W0-lo -> LDS (r4-proven lane-linear layout)
    for (int f = tid; f < 1280; f += 256){
        int c_ = f & 15, ks_ = (f>>4)&3, nt_ = (f>>6)&1, kt_ = f>>7;
        int g_ = (nt_*2 + (c_>>3))*HH + u0 + (c_&7);
        int k_ = kt_*32 + ks_*8;
        const float* p = (k_ < 64) ? (Wih0 + (size_t)g_*DIN + k_)
                                   : (Whh0 + (size_t)g_*HH + (k_ - 64));
        bf16x8 hi_, lo_; split8(*(const float4*)p, *(const float4*)(p+4), hi_, lo_);
        *(bf16x8*)(sh + LW0LO + f*8) = lo_;
    }

    if (tid < 32){
        int gg_ = ((tid>>4)*2 + ((tid>>3)&1))*HH + u0 + (tid & 7);
        b0s[tid] = bih0[gg_] + bhh0[gg_];
        b1s[tid] = bih1[gg_] + bhh1[gg_];
    }
    // ---- zero group h slices (ws poisoned): 32 WGs x 256 thr x 16B = 128KB/group ----
    {
        int idx = ug*256 + tid;               // 0..8191 uint4 over 65536 shorts
        u32x4 z = {0u,0u,0u,0u};
        *(u32x4*)(gbase + (size_t)idx*8) = z;
    }
    // ---- stage x(0) into parity 0 (fragment order + XOR swizzle) ----
    {
        int xr = tid >> 3, k8 = tid & 7;
        const float* xp = x + (size_t)(rbase + xr)*(TT*DIN) + k8*8;
        bf16x8 xh, xl; split8(*(const float4*)xp, *(const float4*)(xp+4), xh, xl);
        short* d = sh + LX + (k8>>2)*1024 + (xr>>4)*512
                 + (((k8&3) ^ (xr&3))<<7) + (xr&15)*8;
        *(bf16x8*)d = xh;
        *(bf16x8*)(d + 2048) = xl;
    }
    group_barrier(flg, ug, 1u);

    // lane A-frag offsets
    const int hoff = mt*512 + l*8;                       // + region + kt*1024
    const int xoff = mt*512 + ((ks ^ (c&3))<<7) + c*8;   // + LX + par*4096 + kt*1024
    const short* b0lo = sh + LW0LO + (nt*64 + ks*16 + c)*8;
    float* gw0 = gbT0 + (nt*16 + c)*33 + mt*16 + ks*4;
    float* gw1 = gbT1 + (nt*16 + c)*33 + mt*16 + ks*4;

    // update mapping: 1 cell/thread
    const int ur = tid >> 3, uu = tid & 7;
    const int fpub = (ug>>2)*1024 + (ur>>4)*512 + ((ug&3)<<7) + (ur&15)*8 + uu;

    float c0s = 0.f, c1s = 0.f;

    for (int k = 0; k <= TT; ++k){
        // ---- stage h0(k-1), h1(k-2): fragment-linear, cached, coalesced ----
        {
            const int p = (k + 1) & 1;
            const u16* s0h = gbase + (0 + p)*8192;
            const u16* s0l = gbase + (2 + p)*8192;
            const u16* s1h = gbase + (4 + p)*8192;
            const u16* s1l = gbase + (6 + p)*8192;
            #pragma unroll
            for (int j = 0; j < 4; ++j){
                int idx = (tid + j*256) * 8;
                *(u32x4*)(sh + LH0HI + idx) = *(const u32x4*)(s0h + idx);
                *(u32x4*)(sh + LH0LO + idx) = *(const u32x4*)(s0l + idx);
                *(u32x4*)(sh + LH1HI + idx) = *(const u32x4*)(s1h + idx);
                *(u32x4*)(sh + LH1LO + idx) = *(const u32x4*)(s1l + idx);
            }
        }
        __syncthreads();

        // ---- phase A: layer0 step t=k ----
        if (k < TT){
            f32x4 ac[4] = {};
            const short* xb = sh + LX + (k&1)*4096 + xoff;
            #pragma unroll
            for (int kt = 0; kt < 10; ++kt){
                bf16x8 ah, al;
                if (kt < 2){
                    ah = *(const bf16x8*)(xb + kt*1024);
                    al = *(const bf16x8*)(xb + kt*1024 + 2048);
                } else {
                    ah = *(const bf16x8*)(sh + LH0HI + (kt-2)*1024 + hoff);
                    al = *(const bf16x8*)(sh + LH0LO + (kt-2)*1024 + hoff);
                }
                bf16x8 wl = *(const bf16x8*)(b0lo + kt*1024);
                const int q = kt & 3;
                ac[q] = MFMA16(ah, w0h[kt], ac[q]);
                ac[q] = MFMA16(al, w0h[kt], ac[q]);
                ac[q] = MFMA16(ah, wl,      ac[q]);
            }
            f32x4 aa = (ac[0] + ac[1]) + (ac[2] + ac[3]);
            *(float4*)gw0 = (float4){aa[0], aa[1], aa[2], aa[3]};
        }
        // ---- phase B: layer1 step t=k-1 (B operands fully in registers) ----
        if (k >= 1){
            f32x4 ac[4] = {};
            #pragma unroll
            for (int kt = 0; kt < 16; ++kt){
                bf16x8 ah, al;
                if (kt < 8){
                    ah = *(const bf16x8*)(sh + LH0HI + kt*1024 + hoff);
                    al = *(const bf16x8*)(sh + LH0LO + kt*1024 + hoff);
                } else {
                    ah = *(const bf16x8*)(sh + LH1HI + (kt-8)*1024 + hoff);
                    al = *(const bf16x8*)(sh + LH1LO + (kt-8)*1024 + hoff);
                }
                const int q = kt & 3;
                ac[q] = MFMA16(ah, w1h[kt], ac[q]);
                ac[q] = MFMA16(al, w1h[kt], ac[q]);
                ac[q] = MFMA16(ah, w1l[kt], ac[q]);
            }
            f32x4 aa = (ac[0] + ac[1]) + (ac[2] + ac[3]);
            *(float4*)gw1 = (float4){aa[0], aa[1], aa[2], aa[3]};
        }
        __syncthreads();

        // ---- cell updates + fragment-order publish ----
        const int pw = (k & 1);
        if (k < TT){
            float gi = gbT0[(uu   )*33 + ur] + b0s[uu];
            float gf = gbT0[(8+uu )*33 + ur] + b0s[8+uu];
            float gg = gbT0[(16+uu)*33 + ur] + b0s[16+uu];
            float go = gbT0[(24+uu)*33 + ur] + b0s[24+uu];
            c0s = sigf(gf)*c0s + sigf(gi)*tanh_fast(gg);
            float hn = sigf(go)*tanh_fast(c0s);
            u16 hh_ = f2bf(hn), hl_ = f2bf(hn - bf2f(hh_));
            gbase[(0 + pw)*8192 + fpub] = hh_;
            gbase[(2 + pw)*8192 + fpub] = hl_;
        }
        if (k >= 1){
            float gi = gbT1[(uu   )*33 + ur] + b1s[uu];
            float gf = gbT1[(8+uu )*33 + ur] + b1s[8+uu];
            float gg = gbT1[(16+uu)*33 + ur] + b1s[16+uu];
            float go = gbT1[(24+uu)*33 + ur] + b1s[24+uu];
            c1s = sigf(gf)*c1s + sigf(gi)*tanh_fast(gg);
            float hn = sigf(go)*tanh_fast(c1s);
            u16 hh_ = f2bf(hn), hl_ = f2bf(hn - bf2f(hh_));
            gbase[(4 + pw)*8192 + fpub] = hh_;
            gbase[(6 + pw)*8192 + fpub] = hl_;
        }
        // ---- prefetch-stage x(k+1) ----
        if (k + 1 < TT){
            int xr = tid >> 3, k8 = tid & 7;
            const float* xp = x + (size_t)(rbase + xr)*(TT*DIN) + (size_t)(k+1)*DIN + k8*8;
            bf16x8 xh, xl; split8(*(const float4*)xp, *(const float4*)(xp+4), xh, xl);
            short* d = sh + LX + ((k+1)&1)*4096 + (k8>>2)*1024 + (xr>>4)*512
                     + (((k8&3) ^ (xr&3))<<7) + (xr&15)*8;
            *(bf16x8*)d = xh;
            *(bf16x8*)(d + 2048) = xl;
        }
        group_barrier(flg, ug, (unsigned)(k + 2));
    }

    // ---- dense head: h1(TT-1) in parity-0 slices (4,6), fragment order ----
    if (ug == 0 && tid < 64){
        int r = tid >> 1, j = tid & 1;
        const u16* hh = gbase + 4*8192;
        const u16* hl = gbase + 6*8192;
        const float* wdp = Wd + j*HH;
        float a = bd[j];
        #pragma unroll 4
        for (int q = 0; q < HH; ++q){
            int f = (q>>5)*1024 + (r>>4)*512 + (((q>>3)&3)<<7) + (r&15)*8 + (q&7);
            a += (bf2f(hh[f]) + bf2f(hl[f])) * wdp[q];
        }
        out[(rbase + r)*2 + j] = a;
    }
}

extern "C" void kernel_launch(void* const* d_in, const int* in_sizes, int n_in,
                              void* d_out, int out_size, void* d_ws, size_t ws_size,
                              hipStream_t stream) {
    const float* x    = (const float*)d_in[0];
    const float* Wih0 = (const float*)d_in[1];
    const float* Whh0 = (const float*)d_in[2];
    const float* bih0 = (const float*)d_in[3];
    const float* bhh0 = (const float*)d_in[4];
    const float* Wih1 = (const float*)d_in[5];
    const float* Whh1 = (const float*)d_in[6];
    const float* bih1 = (const float*)d_in[7];
    const float* bhh1 = (const float*)d_in[8];
    const float* Wd   = (const float*)d_in[9];
    const float* bd   = (const float*)d_in[10];
    float* out = (float*)d_out;

    u32t* flags = (u32t*)d_ws;                     // 8 groups x 32 slots x 64B
    u16* hb = (u16*)((char*)d_ws + 32768);         // 1 MB fragment-order h slices

    hipMemsetAsync(d_ws, 0, 32768, stream);

    hipFuncSetAttribute((const void*)lstm_v11,
                        hipFuncAttributeMaxDynamicSharedMemorySize, LDS_BYTES);

    lstm_v11<<<dim3(256), dim3(256), LDS_BYTES, stream>>>(
        x, Wih0, Whh0, bih0, bhh0, Wih1, Whh1, bih1, bhh1,
        Wd, bd, out, hb, flags);
}

// Round 12
// 18000.827 us; speedup vs baseline: 2.3491x; 1.1872x over previous
//
#include <hip/hip_runtime.h>
#include <math.h>

#define TT 2048
#define DIN 64
#define HH 256

typedef __attribute__((ext_vector_type(8))) short bf16x8;
typedef __attribute__((ext_vector_type(4))) float f32x4;
typedef __attribute__((ext_vector_type(4))) unsigned u32x4;
typedef unsigned short u16;
typedef unsigned u32t;

// ---- LDS layout (shorts, then floats). Only x + W0-lo + gate bufs. ----
#define LX    0                  // [par2][kt2 hi | lo +2048] = 8192 shorts
#define LW0LO 8192               // [kt10][nt2*64+ks*16+c][8] = 10240 shorts
#define SH_SHORTS 18432
#define SH_BYTES (SH_SHORTS*2)   // 36864 B
// floats: gbT0 [32][33]=1056, gbT1 1056, b0s 32, b1s 32
#define LDS_BYTES (SH_BYTES + 2176*4)   // 45568 B

__device__ __forceinline__ u16 f2bf(float f){
    u32t u = __builtin_bit_cast(u32t, f);
    u += 0x7fffu + ((u >> 16) & 1u);   // RNE
    return (u16)(u >> 16);
}
__device__ __forceinline__ float bf2f(u16 h){
    u32t u = ((u32t)h) << 16;
    return __builtin_bit_cast(float, u);
}
__device__ __forceinline__ float sigf(float v){ return 1.0f/(1.0f+__expf(-v)); }
__device__ __forceinline__ float tanh_fast(float v){
    float x = fminf(fmaxf(v, -20.f), 20.f);
    float t = __expf(2.f*x);
    return (t - 1.f) / (t + 1.f);
}
__device__ __forceinline__ void split8(float4 a, float4 b, bf16x8& hi, bf16x8& lo){
    float v[8] = {a.x,a.y,a.z,a.w,b.x,b.y,b.z,b.w};
    #pragma unroll
    for (int j=0;j<8;++j){
        u16 h = f2bf(v[j]);
        hi[j] = (short)h;
        lo[j] = (short)f2bf(v[j] - bf2f(h));
    }
}

// v9/v11-proven: release store to own 64B slot + 32-lane acquire poll.
__device__ __forceinline__ void group_barrier(u32t* flg, int ug, unsigned epoch){
    __syncthreads();
    if (threadIdx.x == 0)
        __hip_atomic_store(flg + ug*16, epoch, __ATOMIC_RELEASE, __HIP_MEMORY_SCOPE_AGENT);
    if (threadIdx.x < 32){
        while (__hip_atomic_load(flg + threadIdx.x*16, __ATOMIC_ACQUIRE, __HIP_MEMORY_SCOPE_AGENT) < epoch)
            __builtin_amdgcn_s_sleep(1);
    }
    __syncthreads();
}

#define MFMA16(a,b,c_) __builtin_amdgcn_mfma_f32_16x16x32_bf16(a,b,c_,0,0,0)

__global__ __launch_bounds__(256, 1)
void lstm_v12(const float* __restrict__ x,
              const float* __restrict__ Wih0, const float* __restrict__ Whh0,
              const float* __restrict__ bih0, const float* __restrict__ bhh0,
              const float* __restrict__ Wih1, const float* __restrict__ Whh1,
              const float* __restrict__ bih1, const float* __restrict__ bhh1,
              const float* __restrict__ Wd,   const float* __restrict__ bd,
              float* __restrict__ out, u16* __restrict__ hb,
              u32t* __restrict__ flags)
{
    extern __shared__ char smem[];
    short* sh  = (short*)smem;
    float* sf  = (float*)(smem + SH_BYTES);
    float* gbT0 = sf;             // [32 col][33]
    float* gbT1 = sf + 1056;      // [32 col][33]
    float* b0s  = sf + 2112;      // [32]
    float* b1s  = sf + 2144;      // [32]

    const int tid = threadIdx.x;
    const int w   = blockIdx.x;
    const int rb  = w & 7;      // row-group (same XCD under %8 round-robin)
    const int ug  = w >> 3;     // unit-group 0..31
    const int rbase = rb * 32;
    const int u0  = ug * 8;

    u32t* flg = flags + rb * 512;

    // Global h: per-group FRAGMENT-ORDER slices, 8192 shorts each.
    // base = rb*65536 + s*8192 ; s: h0hi=0+p, h0lo=2+p, h1hi=4+p, h1lo=6+p
    u16* gbase = hb + (size_t)rb * 65536;

    const int l  = tid & 63;
    const int wv = tid >> 6;
    const int mt = wv >> 1, nt = wv & 1;
    const int c  = l & 15, ks = l >> 4;
    const int gbx = nt*2 + (c >> 3);
    const int g   = gbx*HH + u0 + (c & 7);

    // ---- stationary weight fragments: W0-hi, W1-hi, W1-lo in regs; W0-lo in LDS ----
    bf16x8 w0h[10];
    #pragma unroll
    for (int kt = 0; kt < 10; ++kt){
        int k = kt*32 + ks*8;
        const float* p = (k < 64) ? (Wih0 + (size_t)g*DIN + k)
                                  : (Whh0 + (size_t)g*HH + (k - 64));
        bf16x8 hi_, lo_; split8(*(const float4*)p, *(const float4*)(p+4), hi_, lo_);
        w0h[kt] = hi_;
    }
    bf16x8 w1h[16], w1l[16];
    #pragma unroll
    for (int kt = 0; kt < 16; ++kt){
        int k = kt*32 + ks*8;
        const float* p = (k < 256) ? (Wih1 + (size_t)g*HH + k)
                                   : (Whh1 + (size_t)g*HH + (k - 256));
        bf16x8 hi_, lo_; split8(*(const float4*)p, *(const float4*)(p+4), hi_, lo_);
        w1h[kt] = hi_; w1l[kt] = lo_;
    }
    // W0-lo -> LDS (lane-linear)
    for (int f = tid; f < 1280; f += 256){
        int c_ = f & 15, ks_ = (f>>4)&3, nt_ = (f>>6)&1, kt_ = f>>7;
        int g_ = (nt_*2 + (c_>>3))*HH + u0 + (c_&7);
        int k_ = kt_*32 + ks_*8;
        const float* p = (k_ < 64) ? (Wih0 + (size_t)g_*DIN + k_)
                                   : (Whh0 + (size_t)g_*HH + (k_ - 64));
        bf16x8 hi_, lo_; split8(*(const float4*)p, *(const float4*)(p+4), hi_, lo_);
        *(bf16x8*)(sh + LW0LO + f*8) = lo_;
    }

    if (tid < 32){
        int gg_ = ((tid>>4)*2 + ((tid>>3)&1))*HH + u0 + (tid & 7);
        b0s[tid] = bih0[gg_] + bhh0[gg_];
        b1s[tid] = bih1[gg_] + bhh1[gg_];
    }
    // ---- zero group h slices (ws poisoned) ----
    {
        int idx = ug*256 + tid;               // 8192 uint4 over 65536 shorts
        u32x4 z = {0u,0u,0u,0u};
        *(u32x4*)(gbase + (size_t)idx*8) = z;
    }
    // ---- stage x(0) into parity 0 (fragment order + XOR swizzle) ----
    {
        int xr = tid >> 3, k8 = tid & 7;
        const float* xp = x + (size_t)(rbase + xr)*(TT*DIN) + k8*8;
        bf16x8 xh, xl; split8(*(const float4*)xp, *(const float4*)(xp+4), xh, xl);
        short* d = sh + LX + (k8>>2)*1024 + (xr>>4)*512
                 + (((k8&3) ^ (xr&3))<<7) + (xr&15)*8;
        *(bf16x8*)d = xh;
        *(bf16x8*)(d + 2048) = xl;
    }
    group_barrier(flg, ug, 1u);

    // lane fragment offsets (shorts)
    const int hoff = mt*512 + l*8;                       // + slice*8192 + kt*1024
    const int xoff = mt*512 + ((ks ^ (c&3))<<7) + c*8;
    const short* b0lo = sh + LW0LO + (nt*64 + ks*16 + c)*8;
    float* gw0 = gbT0 + (nt*16 + c)*33 + mt*16 + ks*4;
    float* gw1 = gbT1 + (nt*16 + c)*33 + mt*16 + ks*4;

    // update mapping: 1 cell/thread
    const int ur = tid >> 3, uu = tid & 7;
    const int fpub = (ug>>2)*1024 + (ur>>4)*512 + ((ug&3)<<7) + (ur&15)*8 + uu;

    float c0s = 0.f, c1s = 0.f;

    for (int k = 0; k <= TT; ++k){
        const int p = (k + 1) & 1;
        // ---- h0(k-1) A-fragments: direct coalesced global->reg (reused A+B) ----
        bf16x8 h0h[8], h0l[8];
        {
            const u16* s0h = gbase + (0 + p)*8192 + hoff;
            const u16* s0l = gbase + (2 + p)*8192 + hoff;
            #pragma unroll
            for (int i = 0; i < 8; ++i){
                h0h[i] = *(const bf16x8*)(s0h + i*1024);
                h0l[i] = *(const bf16x8*)(s0l + i*1024);
            }
        }

        // ---- phase A: layer0 step t=k ----
        if (k < TT){
            f32x4 ac[4] = {};
            const short* xb = sh + LX + (k&1)*4096 + xoff;
            #pragma unroll
            for (int kt = 0; kt < 10; ++kt){
                bf16x8 ah, al;
                if (kt < 2){
                    ah = *(const bf16x8*)(xb + kt*1024);
                    al = *(const bf16x8*)(xb + kt*1024 + 2048);
                } else {
                    ah = h0h[kt-2];
                    al = h0l[kt-2];
                }
                bf16x8 wl = *(const bf16x8*)(b0lo + kt*1024);
                const int q = kt & 3;
                ac[q] = MFMA16(ah, w0h[kt], ac[q]);
                ac[q] = MFMA16(al, w0h[kt], ac[q]);
                ac[q] = MFMA16(ah, wl,      ac[q]);
            }
            f32x4 aa = (ac[0] + ac[1]) + (ac[2] + ac[3]);
            *(float4*)gw0 = (float4){aa[0], aa[1], aa[2], aa[3]};
        }
        // ---- phase B: layer1 step t=k-1 (h0 from regs, h1 direct global) ----
        if (k >= 1){
            f32x4 ac[4] = {};
            const u16* s1h = gbase + (4 + p)*8192 + hoff;
            const u16* s1l = gbase + (6 + p)*8192 + hoff;
            #pragma unroll
            for (int kt = 0; kt < 16; ++kt){
                bf16x8 ah, al;
                if (kt < 8){
                    ah = h0h[kt];
                    al = h0l[kt];
                } else {
                    ah = *(const bf16x8*)(s1h + (kt-8)*1024);
                    al = *(const bf16x8*)(s1l + (kt-8)*1024);
                }
                const int q = kt & 3;
                ac[q] = MFMA16(ah, w1h[kt], ac[q]);
                ac[q] = MFMA16(al, w1h[kt], ac[q]);
                ac[q] = MFMA16(ah, w1l[kt], ac[q]);
            }
            f32x4 aa = (ac[0] + ac[1]) + (ac[2] + ac[3]);
            *(float4*)gw1 = (float4){aa[0], aa[1], aa[2], aa[3]};
        }
        __syncthreads();

        // ---- cell updates + fragment-order publish ----
        const int pw = (k & 1);
        if (k < TT){
            float gi = gbT0[(uu   )*33 + ur] + b0s[uu];
            float gf = gbT0[(8+uu )*33 + ur] + b0s[8+uu];
            float gg = gbT0[(16+uu)*33 + ur] + b0s[16+uu];
            float go = gbT0[(24+uu)*33 + ur] + b0s[24+uu];
            c0s = sigf(gf)*c0s + sigf(gi)*tanh_fast(gg);
            float hn = sigf(go)*tanh_fast(c0s);
            u16 hh_ = f2bf(hn), hl_ = f2bf(hn - bf2f(hh_));
            gbase[(0 + pw)*8192 + fpub] = hh_;
            gbase[(2 + pw)*8192 + fpub] = hl_;
        }
        if (k >= 1){
            float gi = gbT1[(uu   )*33 + ur] + b1s[uu];
            float gf = gbT1[(8+uu )*33 + ur] + b1s[8+uu];
            float gg = gbT1[(16+uu)*33 + ur] + b1s[16+uu];
            float go = gbT1[(24+uu)*33 + ur] + b1s[24+uu];
            c1s = sigf(gf)*c1s + sigf(gi)*tanh_fast(gg);
            float hn = sigf(go)*tanh_fast(c1s);
            u16 hh_ = f2bf(hn), hl_ = f2bf(hn - bf2f(hh_));
            gbase[(4 + pw)*8192 + fpub] = hh_;
            gbase[(6 + pw)*8192 + fpub] = hl_;
        }
        // ---- prefetch-stage x(k+1) ----
        if (k + 1 < TT){
            int xr = tid >> 3, k8 = tid & 7;
            const float* xp = x + (size_t)(rbase + xr)*(TT*DIN) + (size_t)(k+1)*DIN + k8*8;
            bf16x8 xh, xl; split8(*(const float4*)xp, *(const float4*)(xp+4), xh, xl);
            short* d = sh + LX + ((k+1)&1)*4096 + (k8>>2)*1024 + (xr>>4)*512
                     + (((k8&3) ^ (xr&3))<<7) + (xr&15)*8;
            *(bf16x8*)d = xh;
            *(bf16x8*)(d + 2048) = xl;
        }
        group_barrier(flg, ug, (unsigned)(k + 2));
    }

    // ---- dense head: h1(TT-1) in parity-0 slices (4,6), fragment order ----
    if (ug == 0 && tid < 64){
        int r = tid >> 1, j = tid & 1;
        const u16* hh = gbase + 4*8192;
        const u16* hl = gbase + 6*8192;
        const float* wdp = Wd + j*HH;
        float a = bd[j];
        #pragma unroll 4
        for (int q = 0; q < HH; ++q){
            int f = (q>>5)*1024 + (r>>4)*512 + (((q>>3)&3)<<7) + (r&15)*8 + (q&7);
            a += (bf2f(hh[f]) + bf2f(hl[f])) * wdp[q];
        }
        out[(rbase + r)*2 + j] = a;
    }
}

extern "C" void kernel_launch(void* const* d_in, const int* in_sizes, int n_in,
                              void* d_out, int out_size, void* d_ws, size_t ws_size,
                              hipStream_t stream) {
    const float* x    = (const float*)d_in[0];
    const float* Wih0 = (const float*)d_in[1];
    const float* Whh0 = (const float*)d_in[2];
    const float* bih0 = (const float*)d_in[3];
    const float* bhh0 = (const float*)d_in[4];
    const float* Wih1 = (const float*)d_in[5];
    const float* Whh1 = (const float*)d_in[6];
    const float* bih1 = (const float*)d_in[7];
    const float* bhh1 = (const float*)d_in[8];
    const float* Wd   = (const float*)d_in[9];
    const float* bd   = (const float*)d_in[10];
    float* out = (float*)d_out;

    u32t* flags = (u32t*)d_ws;                     // 8 groups x 32 slots x 64B
    u16* hb = (u16*)((char*)d_ws + 32768);         // 1 MB fragment-order h slices

    hipMemsetAsync(d_ws, 0, 32768, stream);

    hipFuncSetAttribute((const void*)lstm_v12,
                        hipFuncAttributeMaxDynamicSharedMemorySize, LDS_BYTES);

    lstm_v12<<<dim3(256), dim3(256), LDS_BYTES, stream>>>(
        x, Wih0, Whh0, bih0, bhh0, Wih1, Whh1, bih1, bhh1,
        Wd, bd, out, hb, flags);
}